// Round 6
// baseline (51993.427 us; speedup 1.0000x reference)
//
#include <hip/hip_runtime.h>

typedef unsigned long long u64;

#define BB 16
#define TT 1500
#define NG3 1536
#define GM (BB * TT)   /* 24000 */
#define GK 512
#define LNEPS 1e-5f
#define NCW 96         /* compute WGs per layer */
#define FL 64          /* flag line stride in uints (256B) */
#define HRING 4        /* h0 broadcast ring depth */

// ---------------- helpers ----------------
__device__ __forceinline__ float sigmoidf_(float x) { return 1.f / (1.f + __expf(-x)); }
__device__ __forceinline__ float tanhf_(float x) {
  x = fminf(15.f, fmaxf(-15.f, x));
  float e = __expf(2.f * x);
  return (e - 1.f) / (e + 1.f);
}
__device__ __forceinline__ float red16_(float v) {
  v += __shfl_xor(v, 1, 64); v += __shfl_xor(v, 2, 64);
  v += __shfl_xor(v, 4, 64); v += __shfl_xor(v, 8, 64);
  return v;
}
// XOR-swizzled physical float4-chunk index for a [512]-float LDS row
__device__ __forceinline__ int physc(int lc) { return (lc & ~7) | ((lc ^ (lc >> 3)) & 7); }

__device__ __forceinline__ u64 ldA(const u64* p) {
  return __hip_atomic_load(p, __ATOMIC_RELAXED, __HIP_MEMORY_SCOPE_AGENT);
}
__device__ __forceinline__ void stA8(u64* p, u64 v) {
  __hip_atomic_store(p, v, __ATOMIC_RELAXED, __HIP_MEMORY_SCOPE_AGENT);
}
__device__ __forceinline__ unsigned ldA32(const unsigned* p) {
  return __hip_atomic_load(p, __ATOMIC_RELAXED, __HIP_MEMORY_SCOPE_AGENT);
}
__device__ __forceinline__ void stA32(unsigned* p, unsigned v) {
  __hip_atomic_store(p, v, __ATOMIC_RELAXED, __HIP_MEMORY_SCOPE_AGENT);
}
__device__ __forceinline__ u64 pk(unsigned tag, float v) {
  return ((u64)tag << 32) | (u64)__float_as_uint(v);
}

// Batched tagged poll: 32 u64 at base[l16*4 + i*64 + q]; spin until ALL tags == want.
__device__ __forceinline__ void poll32(const u64* __restrict__ base, int l16, unsigned want,
                                       float* dst) {
  const u64* p = base + l16 * 4;
  for (;;) {
    unsigned bad = 0;
#pragma unroll
    for (int i = 0; i < 8; ++i) {
      u64 a = ldA(p + i * 64 + 0);
      u64 b = ldA(p + i * 64 + 1);
      u64 c = ldA(p + i * 64 + 2);
      u64 d = ldA(p + i * 64 + 3);
      dst[i * 4 + 0] = __uint_as_float((unsigned)a);
      dst[i * 4 + 1] = __uint_as_float((unsigned)b);
      dst[i * 4 + 2] = __uint_as_float((unsigned)c);
      dst[i * 4 + 3] = __uint_as_float((unsigned)d);
      bad |= ((unsigned)(a >> 32) ^ want) | ((unsigned)(b >> 32) ^ want) |
             ((unsigned)(c >> 32) ^ want) | ((unsigned)(d >> 32) ^ want);
    }
    if (!bad) return;
    __builtin_amdgcn_s_sleep(1);
  }
}

// ---------------- big GEMM: C[M,N] = A[M,K] @ W[N,K]^T (fp32) ----------------
__global__ __launch_bounds__(256) void gemm_nt(const float* __restrict__ A,
                                               const float* __restrict__ W,
                                               float* __restrict__ C) {
  __shared__ __align__(16) float As[32][68];
  __shared__ __align__(16) float Ws[32][68];
  const int m0 = blockIdx.x * 64;
  const int n0 = blockIdx.y * 64;
  const int tid = threadIdx.x;
  const int tm = tid & 15, tn = tid >> 4;
  float acc[4][4] = {};
  for (int k0 = 0; k0 < GK; k0 += 32) {
#pragma unroll
    for (int u = 0; u < 2; ++u) {
      int idx = tid + u * 256;
      int r = idx >> 3;
      int kq = (idx & 7) * 4;
      float4 a = *reinterpret_cast<const float4*>(&A[(size_t)(m0 + r) * GK + k0 + kq]);
      As[kq + 0][r] = a.x; As[kq + 1][r] = a.y; As[kq + 2][r] = a.z; As[kq + 3][r] = a.w;
      float4 w = *reinterpret_cast<const float4*>(&W[(size_t)(n0 + r) * GK + k0 + kq]);
      Ws[kq + 0][r] = w.x; Ws[kq + 1][r] = w.y; Ws[kq + 2][r] = w.z; Ws[kq + 3][r] = w.w;
    }
    __syncthreads();
#pragma unroll
    for (int kk = 0; kk < 32; ++kk) {
      float a[4], w[4];
      *reinterpret_cast<float4*>(a) = *reinterpret_cast<const float4*>(&As[kk][tm * 4]);
      *reinterpret_cast<float4*>(w) = *reinterpret_cast<const float4*>(&Ws[kk][tn * 4]);
#pragma unroll
      for (int i = 0; i < 4; ++i)
#pragma unroll
        for (int q = 0; q < 4; ++q)
          acc[i][q] = fmaf(a[i], w[q], acc[i][q]);
    }
    __syncthreads();
  }
#pragma unroll
  for (int i = 0; i < 4; ++i) {
    float4 v = make_float4(acc[i][0], acc[i][1], acc[i][2], acc[i][3]);
    *reinterpret_cast<float4*>(&C[(size_t)(m0 + tm * 4 + i) * NG3 + n0 + tn * 4]) = v;
  }
}

// ---------------- fused 2-layer GRU scan, 1 tagged exchange per step/layer ----
// WG 0..95  : layer 0 (16 cols each, Wh0 in regs, redundant phase-2, h in LDS)
// WG 96..191: layer 1 (16 cols, Wi1+Wh1 in regs, dual matvec, redundant phase-2)
// G0 u64[2][16][1536], G1 u64[2][16][2048] (cols 1536..2047 = x_n), each word
// self-tagged (tag=t+1 in high 32 bits) -> no fences, no drains, no flags.
// Hb0 u64[4][16][512]: tagged h0 ring L0->L1; prog1: L1 copy progress (throttle).
__global__ __launch_bounds__(256, 1) void gru_fused(
    const float* __restrict__ Wh0, const float* __restrict__ Wi1,
    const float* __restrict__ Wh1, const float* __restrict__ X0,
    const float* __restrict__ lnw, const float* __restrict__ lnb,
    float* __restrict__ out, u64* __restrict__ G0, u64* __restrict__ G1,
    u64* __restrict__ Hb0, unsigned* __restrict__ prog1) {
  __shared__ __align__(16) float shA[BB][512];  // this layer's h (swizzled chunks)
  __shared__ __align__(16) float shB[BB][512];  // L1 only: h0(t)

  const int tid = threadIdx.x, wg = blockIdx.x;
  const int lane = tid & 63, wv = tid >> 6;
  const int ks = lane & 15, cq = lane >> 4;     // phase-1: K-chunk / col-in-wave
  const int b2 = wv * 4 + (lane >> 4);          // phase-2: batch row
  const int l16 = lane & 15;
  const int rr = tid >> 4, cc = (tid & 15) * 32;  // h0-copy: row / col base

  const bool L1 = wg >= NCW;
  const int wgl = L1 ? wg - NCW : wg;
  const int col = wgl * 16 + wv * 4 + cq;

  float wh[32], wi[32];
  {
    const float* Wp = (L1 ? Wh1 : Wh0) + (size_t)col * 512 + ks * 32;
#pragma unroll
    for (int q = 0; q < 8; ++q) *(float4*)&wh[q * 4] = *(const float4*)&Wp[q * 4];
    if (L1) {
      const float* Wq = Wi1 + (size_t)col * 512 + ks * 32;
#pragma unroll
      for (int q = 0; q < 8; ++q) *(float4*)&wi[q * 4] = *(const float4*)&Wq[q * 4];
    } else {
#pragma unroll
      for (int q = 0; q < 32; ++q) wi[q] = 0.f;
    }
  }
  for (int idx = tid; idx < BB * 512; idx += 256) (&shA[0][0])[idx] = 0.f;
  __syncthreads();

  u64* Gb = L1 ? G1 : G0;
  const int GW = L1 ? 2048 : 1536;
  const float* lnwL = lnw + (L1 ? 1536 : 0);
  const float* lnbL = lnb + (L1 ? 1536 : 0);

  for (int t = 0; t < TT; ++t) {
    const unsigned want = (unsigned)(t + 1);
    float xv = 0.f;
    float xn[32];

    if (!L1) {
      // writers: ring throttle for this step's h0 store into slot t&3
      if (wgl < BB && t >= HRING) {
        if (tid < NCW) {
          const unsigned w2 = (unsigned)(t - (HRING - 1));
          while (ldA32(&prog1[(size_t)tid * FL]) < w2) __builtin_amdgcn_s_sleep(2);
        }
        __syncthreads();
      }
      // early X0 loads (plain cached; L2/L3-resident rows), consumed much later
      if (col < 1024) xv = X0[((size_t)ks * TT + t) * NG3 + col];
      const float* Xr = X0 + ((size_t)b2 * TT + t) * NG3 + 1024 + l16 * 4;
#pragma unroll
      for (int i = 0; i < 8; ++i)
        *(float4*)&xn[i * 4] = *(const float4*)&Xr[i * 64];
    } else {
      // poll + copy h0(t) ring slot -> shB
      const u64* src = Hb0 + (size_t)(t & (HRING - 1)) * (BB * 512) + (size_t)rr * 512 + cc;
      float v[32];
      for (;;) {
        unsigned bad = 0;
#pragma unroll
        for (int i = 0; i < 32; ++i) {
          u64 w = ldA(src + i);
          v[i] = __uint_as_float((unsigned)w);
          bad |= (unsigned)(w >> 32) ^ want;
        }
        if (!bad) break;
        __builtin_amdgcn_s_sleep(1);
      }
#pragma unroll
      for (int j = 0; j < 8; ++j)
        *(float4*)&shB[rr][physc((cc >> 2) + j) << 2] = *(float4*)&v[j * 4];
      __syncthreads();
      if (tid == 0) stA32(&prog1[(size_t)wgl * FL], want);
    }

    // ---- phase 1: matvec(s) over local LDS h ----
    float gh = 0.f, gx = 0.f;
#pragma unroll 2
    for (int b = 0; b < 16; ++b) {
      float p = 0.f, p2 = 0.f;
#pragma unroll
      for (int i = 0; i < 8; ++i) {
        const int off = ((ks << 3) | ((i ^ ks) & 7)) << 2;
        float hv[4];
        *(float4*)hv = *(const float4*)&shA[b][off];
        p = fmaf(hv[0], wh[i * 4 + 0], p);
        p = fmaf(hv[1], wh[i * 4 + 1], p);
        p = fmaf(hv[2], wh[i * 4 + 2], p);
        p = fmaf(hv[3], wh[i * 4 + 3], p);
        if (L1) {
          float bv[4];
          *(float4*)bv = *(const float4*)&shB[b][off];
          p2 = fmaf(bv[0], wi[i * 4 + 0], p2);
          p2 = fmaf(bv[1], wi[i * 4 + 1], p2);
          p2 = fmaf(bv[2], wi[i * 4 + 2], p2);
          p2 = fmaf(bv[3], wi[i * 4 + 3], p2);
        }
      }
      p = red16_(p);
      if (L1) p2 = red16_(p2);
      if (ks == b) { gh = p; gx = p2; }
    }
    // ---- tagged gate store (fire-and-forget; tag travels with the data) ----
    {
      u64* Gw = Gb + (size_t)(t & 1) * (BB * GW) + (size_t)ks * GW;
      if (!L1) {
        stA8(&Gw[col], pk(want, gh + xv));
      } else if (col < 1024) {
        stA8(&Gw[col], pk(want, gh + gx));
      } else {
        stA8(&Gw[col], pk(want, gh));        // h_n
        stA8(&Gw[col + 512], pk(want, gx));  // x_n
      }
    }

    // ---- phase 2: redundant LN + gates + h update (all 16 b across WG) ----
    const u64* Grow = Gb + (size_t)(t & 1) * (BB * GW) + (size_t)b2 * GW;

    float gr[32];
    poll32(Grow, l16, want, gr);
    float s = 0.f, s2 = 0.f;
#pragma unroll
    for (int k = 0; k < 32; ++k) { s += gr[k]; s2 += gr[k] * gr[k]; }
    s = red16_(s); s2 = red16_(s2);
    const float mr = s * (1.f / 512.f);
    const float rsr = rsqrtf(s2 * (1.f / 512.f) - mr * mr + LNEPS);
    float rv[32];
#pragma unroll
    for (int i = 0; i < 8; ++i)
#pragma unroll
      for (int q = 0; q < 4; ++q) {
        int k = i * 4 + q, j2 = l16 * 4 + i * 64 + q;
        rv[k] = sigmoidf_((gr[k] - mr) * rsr * lnwL[j2] + lnbL[j2]);
      }

    float gn[32];
    poll32(Grow + 1024, l16, want, gn);
    if (L1) poll32(Grow + 1536, l16, want, xn);
    float np_[32];
    s = 0.f; s2 = 0.f;
#pragma unroll
    for (int k = 0; k < 32; ++k) {
      float v = xn[k] + rv[k] * gn[k];
      np_[k] = v; s += v; s2 += v * v;
    }
    s = red16_(s); s2 = red16_(s2);
    const float mn = s * (1.f / 512.f);
    const float rsn = rsqrtf(s2 * (1.f / 512.f) - mn * mn + LNEPS);

    float gz[32];
    poll32(Grow + 512, l16, want, gz);
    s = 0.f; s2 = 0.f;
#pragma unroll
    for (int k = 0; k < 32; ++k) { s += gz[k]; s2 += gz[k] * gz[k]; }
    s = red16_(s); s2 = red16_(s2);
    const float mz = s * (1.f / 512.f);
    const float rsz = rsqrtf(s2 * (1.f / 512.f) - mz * mz + LNEPS);

#pragma unroll
    for (int i = 0; i < 8; ++i) {
      int j2 = l16 * 4 + i * 64;
      int off = physc(l16 + i * 16) << 2;
      float hold[4], res[4], hv4[4];
      *(float4*)hold = *(const float4*)&shA[b2][off];
      if (L1) *(float4*)res = *(const float4*)&shB[b2][off];
#pragma unroll
      for (int q = 0; q < 4; ++q) {
        int k = i * 4 + q;
        float z = sigmoidf_((gz[k] - mz) * rsz * lnwL[512 + j2 + q] + lnbL[512 + j2 + q]);
        float n = tanhf_((np_[k] - mn) * rsn * lnwL[1024 + j2 + q] + lnbL[1024 + j2 + q]);
        float h = (1.f - z) * n + z * hold[q];
        if (L1) h += res[q];
        hv4[q] = h;
      }
      *(float4*)&shA[b2][off] = *(float4*)hv4;
      if (!L1) {
        if (wgl == b2) {  // broadcast tagged h0(t) row
          u64* Hw = Hb0 + (size_t)(t & (HRING - 1)) * (BB * 512) + (size_t)b2 * 512 + j2;
#pragma unroll
          for (int q = 0; q < 4; ++q) stA8(&Hw[q], pk(want, hv4[q]));
        }
      } else if (wgl == b2) {
        *(float4*)&out[((size_t)b2 * TT + t) * 512 + j2] = *(float4*)hv4;
      }
    }
    __syncthreads();  // shA(t) complete before next step's matvec
  }
}

// ---------------- launch ----------------
extern "C" void kernel_launch(void* const* d_in, const int* in_sizes, int n_in,
                              void* d_out, int out_size, void* d_ws, size_t ws_size,
                              hipStream_t stream) {
  (void)in_sizes; (void)n_in; (void)out_size; (void)ws_size;
  const float* x   = (const float*)d_in[0];
  const float* Wi  = (const float*)d_in[1];  // [2][1536][512]
  const float* Wh  = (const float*)d_in[2];  // [2][1536][512]
  const float* lnw = (const float*)d_in[3];  // [2][3][512]
  const float* lnb = (const float*)d_in[4];
  float* out = (float*)d_out;

  float* X0 = (float*)d_ws;                       // [24000][1536] f32
  u64* G0  = (u64*)(X0 + (size_t)GM * NG3);       // [2][16][1536]
  u64* G1  = G0 + 2 * BB * NG3;                   // [2][16][2048]
  u64* Hb0 = G1 + 2 * BB * 2048;                  // [4][16][512]
  unsigned* prog1 = (unsigned*)(Hb0 + HRING * BB * 512);  // [96][64]

  size_t clear_bytes = (size_t)(2 * BB * NG3 + 2 * BB * 2048 + HRING * BB * 512) * 8 +
                       (size_t)NCW * FL * 4;
  hipMemsetAsync(G0, 0, clear_bytes, stream);

  dim3 ggrid(GM / 64, NG3 / 64);
  gemm_nt<<<ggrid, 256, 0, stream>>>(x, Wi, X0);  // layer-0 input gates
  gru_fused<<<2 * NCW, 256, 0, stream>>>(
      Wh, Wi + (size_t)NG3 * 512, Wh + (size_t)NG3 * 512, X0, lnw, lnb, out,
      G0, G1, Hb0, prog1);
}